// Round 3
// baseline (1689.946 us; speedup 1.0000x reference)
//
#include <hip/hip_runtime.h>

// CapsAll on MI355X — round 7: counted-vmcnt 3-deep pipeline (T3+T4) in
// k1_all and k2_allr. Round-6 post-mortem: __syncthreads' vmcnt(0) drain
// every K-step was the stall (2-phase ceiling, m233). Now: raw s_barrier +
// s_waitcnt vmcnt(L) lgkmcnt(0), loads stay in flight across barriers,
// 3 LDS buffers, stage-after-barrier (write-after-read safe via the
// explicit lgkmcnt(0) drain before each barrier).
//
// Numerics: identical operations in identical order vs round 6 (absmax
// expected unchanged at ~4.8e-7).
//
//   k0h: fp32 -> bf16(hi) plane  (W1, W2, x)
//   k0t: cw [r][k][n] fp32 -> cwh/cwl [r][n][k] bf16 (post-loop, overlays Hh)
//   k1_all: hbar = relu(Xbf @ WS1_r^T) for all 8 r, 3-deep counted pipeline
//   k2_allr: scores GEMM + col-softmax + m for 4 r per block, 3-deep
//            counted pipeline, u-permuted B rows -> coalesced float4 x loads
//   k3:  votes = m @ cw, 2-pass MFMA (fallback: fp32 VALU kernel)
//   k4:  dynamic routing (3 iters) + norms
//
// ws layout, big path (>=188 MB): m 4 @0 | votes 8 @4 | W1h 8 @12 |
//   W2h 8 @20 | Xbf 64 @28 | HhA 64 @92 ... after main loop HhA dies and
//   CWh 32 @92 | CWl 32 @124 overlay it.

typedef __attribute__((ext_vector_type(8))) short bf16x8;
typedef __attribute__((ext_vector_type(8))) unsigned short u16x8;
typedef __attribute__((ext_vector_type(4))) float f32x4;

#define LDT 40  // LDS row stride (bf16) for the legacy reg-staged kernels

__device__ __forceinline__ unsigned short f2bf(float f) {
    unsigned u = __float_as_uint(f);
    u += 0x7FFF + ((u >> 16) & 1);           // round-to-nearest-even
    return (unsigned short)(u >> 16);
}
__device__ __forceinline__ float bf2f(unsigned short h) {
    return __uint_as_float(((unsigned)h) << 16);
}

// async global->LDS, 16 B per lane. LDS dest wave-uniform base; HW scatters
// lane*16. Global src is per-lane.
typedef __attribute__((address_space(1))) void gvoid;
typedef __attribute__((address_space(3))) void lvoid;
__device__ __forceinline__ void gll16(const unsigned short* g, unsigned short* l) {
    __builtin_amdgcn_global_load_lds((gvoid*)g, (lvoid*)l, 16, 0, 0);
}

// ---------------- k0h: elementwise fp32 -> bf16 hi plane ----------------
__global__ __launch_bounds__(256) void k0_hi(const float* __restrict__ src,
                                             unsigned short* __restrict__ hi,
                                             int n4) {
    int i = blockIdx.x * 256 + threadIdx.x;
    if (i >= n4) return;
    float4 v = ((const float4*)src)[i];
    ushort4 h;
    h.x = f2bf(v.x); h.y = f2bf(v.y); h.z = f2bf(v.z); h.w = f2bf(v.w);
    ((ushort4*)hi)[i] = h;
}

// ------- k0t: cw [r][k=1024][n=2048] fp32 -> [r][n][k] bf16 hi+lo -------
__global__ __launch_bounds__(256) void k0_tsplit(const float* __restrict__ cw,
                                                 unsigned short* __restrict__ ch,
                                                 unsigned short* __restrict__ cl) {
    __shared__ unsigned short Th[64 * 68], Tl[64 * 68];
    const int tid = threadIdx.x;
    const int n0 = blockIdx.x * 64, k0 = blockIdx.y * 64, r = blockIdx.z;
    const float* src = cw + (size_t)r * 1024 * 2048;
#pragma unroll
    for (int p = 0; p < 4; p++) {
        const int kl = p * 16 + (tid >> 4);
        const int nl = (tid & 15) * 4;
        float4 v = *(const float4*)(src + (size_t)(k0 + kl) * 2048 + n0 + nl);
        float vv[4] = {v.x, v.y, v.z, v.w};
#pragma unroll
        for (int e = 0; e < 4; e++) {
            unsigned short h = f2bf(vv[e]);
            Th[(nl + e) * 68 + kl] = h;
            Tl[(nl + e) * 68 + kl] = f2bf(vv[e] - bf2f(h));
        }
    }
    __syncthreads();
    const int nl = tid >> 2, kl = (tid & 3) * 16;
    unsigned short* dh = ch + ((size_t)r * 2048 + n0 + nl) * 1024 + k0 + kl;
    unsigned short* dl = cl + ((size_t)r * 2048 + n0 + nl) * 1024 + k0 + kl;
    *(u16x8*)(dh)     = *(const u16x8*)&Th[nl * 68 + kl];
    *(u16x8*)(dh + 8) = *(const u16x8*)&Th[nl * 68 + kl + 8];
    *(u16x8*)(dl)     = *(const u16x8*)&Tl[nl * 68 + kl];
    *(u16x8*)(dl + 8) = *(const u16x8*)&Tl[nl * 68 + kl + 8];
}

// -------- k1_all: hbar = relu(Xbf @ W1_r^T), 3-deep counted pipeline ----
// 128x128 tile, BK=32, 4 waves. grid (64 m, 4 n, 8 r): id%8 = m%8 so all
// (n,r) blocks of an m-slice share an XCD (X rows L2-hot).
__global__ __launch_bounds__(256) void k1_all(
    const unsigned short* __restrict__ Xb,   // chunk base [8192][1024]
    const unsigned short* __restrict__ W1h,  // [8][512][1024]
    unsigned short* __restrict__ HhA) {      // [8][8192][512]
    __shared__ __align__(16) unsigned short Ah[3][128 * 32];  // 24 KB
    __shared__ __align__(16) unsigned short Bh[3][128 * 32];  // 24 KB
    const int tid = threadIdx.x;
    const int m0 = blockIdx.x * 128, n0 = blockIdx.y * 128, r = blockIdx.z;
    const int wave = tid >> 6, lane = tid & 63;
    const int wm = (wave >> 1) * 64, wn = (wave & 1) * 64;
    const int lx = lane & 15, qd = lane >> 4;
    const int rl = lane >> 2, cl = (lane & 3) * 8;   // 16 rows/KB, 16B/lane

    f32x4 acc[4][4];
#pragma unroll
    for (int i = 0; i < 4; i++)
#pragma unroll
        for (int j = 0; j < 4; j++) acc[i][j] = (f32x4){0.f, 0.f, 0.f, 0.f};

    const unsigned short* asrc = Xb + (size_t)(m0 + rl) * 1024 + cl;
    const unsigned short* bsrc =
        W1h + (size_t)r * 512 * 1024 + (size_t)(n0 + rl) * 1024 + cl;

    // L = 4 gll16 per wave per stage
#define K1_STG(Q, KK)                                                  \
    do {                                                               \
        _Pragma("unroll") for (int s = 0; s < 2; s++) {                \
            const int c = wave * 2 + s;                                \
            gll16(asrc + (size_t)c * 16 * 1024 + (KK), &Ah[Q][c * 512]); \
            gll16(bsrc + (size_t)c * 16 * 1024 + (KK), &Bh[Q][c * 512]); \
        }                                                              \
    } while (0)

#define K1_CMP(Q)                                                          \
    do {                                                                   \
        bf16x8 fa[4], fb[4];                                               \
        _Pragma("unroll") for (int i = 0; i < 4; i++) {                    \
            fa[i] = *(const bf16x8*)&Ah[Q][(wm + 16 * i + lx) * 32 + 8 * qd]; \
            fb[i] = *(const bf16x8*)&Bh[Q][(wn + 16 * i + lx) * 32 + 8 * qd]; \
        }                                                                  \
        _Pragma("unroll") for (int i = 0; i < 4; i++)                      \
            _Pragma("unroll") for (int j = 0; j < 4; j++)                  \
                acc[i][j] = __builtin_amdgcn_mfma_f32_16x16x32_bf16(       \
                    fa[i], fb[j], acc[i][j], 0, 0, 0);                     \
    } while (0)

#define K1_SYNC(VM)                                                 \
    asm volatile("s_waitcnt vmcnt(" VM ") lgkmcnt(0)" ::: "memory"); \
    __builtin_amdgcn_s_barrier();                                   \
    __builtin_amdgcn_sched_barrier(0)

    K1_STG(0, 0);
    K1_STG(1, 32);
    // main loop t = 0..29 (stage t+2 always valid)
    for (int tt = 0; tt < 30; tt += 3) {
        K1_SYNC("4"); K1_STG(2, (tt + 2) * 32); K1_CMP(0);
        K1_SYNC("4"); K1_STG(0, (tt + 3) * 32); K1_CMP(1);
        K1_SYNC("4"); K1_STG(1, (tt + 4) * 32); K1_CMP(2);
    }
    K1_SYNC("4"); K1_CMP(0);   // t=30: no stage; stage(31) stays in flight
    K1_SYNC("0"); K1_CMP(1);   // t=31: drain
#undef K1_SYNC
#undef K1_CMP
#undef K1_STG

    unsigned short* Hh = HhA + (size_t)r * 8192 * 512;
#pragma unroll
    for (int i = 0; i < 4; i++)
#pragma unroll
        for (int j = 0; j < 4; j++) {
            const int col = n0 + wn + 16 * j + lx;
#pragma unroll
            for (int p2 = 0; p2 < 4; p2++) {
                const int row = m0 + wm + 16 * i + 4 * qd + p2;
                Hh[(size_t)row * 512 + col] = f2bf(fmaxf(acc[i][j][p2], 0.f));
            }
        }
}

// ---- k1 fallback (fp32 x, reg-staged): unchanged round-4 kernel --------
template <int XBF>
__global__ __launch_bounds__(256) void k1_hbar_mfma(
    const void* __restrict__ Xv,
    const unsigned short* __restrict__ Wh,
    unsigned short* __restrict__ Hh) {
    __shared__ unsigned short Ah[128 * LDT];
    __shared__ unsigned short Bh[128 * LDT];
    const int tid = threadIdx.x;
    const int m0 = blockIdx.x * 128, n0 = blockIdx.y * 128;
    const int wave = tid >> 6, lane = tid & 63;
    const int wm = (wave >> 1) * 64, wn = (wave & 1) * 64;
    const int lx = lane & 15, qd = lane >> 4;
    const int srow = tid >> 1, scol = (tid & 1) * 16;

    f32x4 acc[4][4];
#pragma unroll
    for (int i = 0; i < 4; i++)
#pragma unroll
        for (int j = 0; j < 4; j++) acc[i][j] = (f32x4){0.f, 0.f, 0.f, 0.f};

    const unsigned short* whrow = Wh + (size_t)(n0 + srow) * 1024 + scol;
    unsigned short* ah = &Ah[srow * LDT + scol];
    unsigned short* bh = &Bh[srow * LDT + scol];

    for (int k0 = 0; k0 < 1024; k0 += 32) {
        if (XBF) {
            const unsigned short* xrow =
                (const unsigned short*)Xv + (size_t)(m0 + srow) * 1024 + scol;
            u16x8 a0 = *(const u16x8*)(xrow + k0);
            u16x8 a1 = *(const u16x8*)(xrow + k0 + 8);
            *(u16x8*)(ah) = a0; *(u16x8*)(ah + 8) = a1;
        } else {
            const float* xrow = (const float*)Xv + (size_t)(m0 + srow) * 1024 + scol;
            float4 v0 = *(const float4*)(xrow + k0);
            float4 v1 = *(const float4*)(xrow + k0 + 4);
            float4 v2 = *(const float4*)(xrow + k0 + 8);
            float4 v3 = *(const float4*)(xrow + k0 + 12);
            float vv[16] = {v0.x, v0.y, v0.z, v0.w, v1.x, v1.y, v1.z, v1.w,
                            v2.x, v2.y, v2.z, v2.w, v3.x, v3.y, v3.z, v3.w};
            u16x8 p0, p1;
#pragma unroll
            for (int e = 0; e < 8; e++) p0[e] = f2bf(vv[e]);
#pragma unroll
            for (int e = 0; e < 8; e++) p1[e] = f2bf(vv[8 + e]);
            *(u16x8*)(ah) = p0; *(u16x8*)(ah + 8) = p1;
        }
        u16x8 b0 = *(const u16x8*)(whrow + k0);
        u16x8 b1 = *(const u16x8*)(whrow + k0 + 8);
        *(u16x8*)(bh) = b0; *(u16x8*)(bh + 8) = b1;
        __syncthreads();

        bf16x8 fa[4], fb[4];
#pragma unroll
        for (int i = 0; i < 4; i++) {
            fa[i] = *(const bf16x8*)&Ah[(wm + 16 * i + lx) * LDT + 8 * qd];
            fb[i] = *(const bf16x8*)&Bh[(wn + 16 * i + lx) * LDT + 8 * qd];
        }
#pragma unroll
        for (int i = 0; i < 4; i++)
#pragma unroll
            for (int j = 0; j < 4; j++)
                acc[i][j] = __builtin_amdgcn_mfma_f32_16x16x32_bf16(fa[i], fb[j], acc[i][j], 0, 0, 0);
        __syncthreads();
    }

#pragma unroll
    for (int i = 0; i < 4; i++)
#pragma unroll
        for (int j = 0; j < 4; j++) {
            const int col = n0 + wn + 16 * j + lx;
#pragma unroll
            for (int p = 0; p < 4; p++) {
                const int row = m0 + wm + 16 * i + 4 * qd + p;
                Hh[(size_t)row * 512 + col] = f2bf(fmaxf(acc[i][j][p], 0.f));
            }
        }
}

// ------- k2_allr: scores GEMM + col-softmax + m, 4 r per block ----------
// grid (32 b, 16 u, 2 r-halves). 3-deep counted pipeline; x slice L2-hot
// across the 4-r loop.
__global__ __launch_bounds__(256) void k2_allr(
    const unsigned short* __restrict__ HhA,   // [8][8192][512] chunk-local
    const unsigned short* __restrict__ W2h,   // [8][1024][512]
    const float* __restrict__ x, float* __restrict__ m_out, int b0) {
    __shared__ __align__(16) unsigned short Ah[3][256 * 32];  // 48 KB
    __shared__ __align__(16) unsigned short Bh[3][64 * 32];   // 12 KB
    __shared__ float mred[256], sred[256], pred[256];
    const int tid = threadIdx.x;
    const int b_local = blockIdx.x, b = b0 + b_local;
    const int u0 = blockIdx.y * 64;
    const int r_base = blockIdx.z * 4;
    const int wave = tid >> 6, lane = tid & 63;
    const int lx = lane & 15, qd = lane >> 4;
    const int rl = lane >> 2, cl = (lane & 3) * 8;
    const int ub = wave * 16 + rl;                        // B LDS row this lane fills
    const int uperm = 4 * (ub & 15) + (ub >> 4);          // u-permutation

    for (int rr = 0; rr < 4; ++rr) {
        const int r = r_base + rr;
        const unsigned short* asrc =
            HhA + (size_t)r * 8192 * 512 + (size_t)(b_local * 256 + rl) * 512 + cl;
        const unsigned short* bsrc =
            W2h + (size_t)r * 1024 * 512 + (size_t)(u0 + uperm) * 512 + cl;

        f32x4 acc[4][4];
#pragma unroll
        for (int i = 0; i < 4; i++)
#pragma unroll
            for (int j = 0; j < 4; j++) acc[i][j] = (f32x4){0.f, 0.f, 0.f, 0.f};

        // L = 5 gll16 per wave per stage
#define K2_STG(Q, KK)                                                   \
    do {                                                                \
        _Pragma("unroll") for (int s = 0; s < 4; s++) {                 \
            const int c = wave * 4 + s;                                 \
            gll16(asrc + (size_t)c * 16 * 512 + (KK), &Ah[Q][c * 512]); \
        }                                                               \
        gll16(bsrc + (KK), &Bh[Q][wave * 512]);                         \
    } while (0)

#define K2_CMP(Q)                                                              \
    do {                                                                       \
        bf16x8 fa[4], fb[4];                                                   \
        _Pragma("unroll") for (int i = 0; i < 4; i++) {                        \
            fa[i] = *(const bf16x8*)&Ah[Q][(64 * wave + 16 * i + lx) * 32 + 8 * qd]; \
            fb[i] = *(const bf16x8*)&Bh[Q][(16 * i + lx) * 32 + 8 * qd];       \
        }                                                                      \
        _Pragma("unroll") for (int i = 0; i < 4; i++)                          \
            _Pragma("unroll") for (int j = 0; j < 4; j++)                      \
                acc[i][j] = __builtin_amdgcn_mfma_f32_16x16x32_bf16(           \
                    fa[i], fb[j], acc[i][j], 0, 0, 0);                         \
    } while (0)

#define K2_SYNC(VM)                                                 \
    asm volatile("s_waitcnt vmcnt(" VM ") lgkmcnt(0)" ::: "memory"); \
    __builtin_amdgcn_s_barrier();                                   \
    __builtin_amdgcn_sched_barrier(0)

        K2_STG(0, 0);
        K2_STG(1, 32);
        // t = 0..11 (stage t+2 <= 13 valid)
        for (int tt = 0; tt < 12; tt += 3) {
            K2_SYNC("5"); K2_STG(2, (tt + 2) * 32); K2_CMP(0);
            K2_SYNC("5"); K2_STG(0, (tt + 3) * 32); K2_CMP(1);
            K2_SYNC("5"); K2_STG(1, (tt + 4) * 32); K2_CMP(2);
        }
        K2_SYNC("5"); K2_STG(2, 14 * 32); K2_CMP(0);  // t=12
        K2_SYNC("5"); K2_STG(0, 15 * 32); K2_CMP(1);  // t=13
        K2_SYNC("5"); K2_CMP(2);                      // t=14 (stage 15 in flight)
        K2_SYNC("0"); K2_CMP(0);                      // t=15 drain
#undef K2_SYNC
#undef K2_CMP
#undef K2_STG

        // ---- column max over t: per-lane -> cross-quad -> cross-wave ----
        float cm[4];
#pragma unroll
        for (int j = 0; j < 4; j++) {
            float mx = acc[0][j][0];
#pragma unroll
            for (int i = 0; i < 4; i++)
#pragma unroll
                for (int p2 = 0; p2 < 4; p2++) mx = fmaxf(mx, acc[i][j][p2]);
            mx = fmaxf(mx, __shfl_xor(mx, 16, 64));
            mx = fmaxf(mx, __shfl_xor(mx, 32, 64));
            if (qd == 0) mred[wave * 64 + 16 * j + lx] = mx;
        }
        __syncthreads();
#pragma unroll
        for (int j = 0; j < 4; j++) {
            const int c = 16 * j + lx;
            cm[j] = fmaxf(fmaxf(mred[c], mred[64 + c]),
                          fmaxf(mred[128 + c], mred[192 + c]));
        }

        // ---- exp + weighted sum against x (float4 coalesced, L2-hot) ----
        float ds[4] = {0.f, 0.f, 0.f, 0.f}, pm[4] = {0.f, 0.f, 0.f, 0.f};
        const float* xb = x + (size_t)b * 256 * 1024 + u0 + 4 * lx;
#pragma unroll
        for (int i = 0; i < 4; i++) {
#pragma unroll
            for (int p2 = 0; p2 < 4; p2++) {
                const int t = 64 * wave + 16 * i + 4 * qd + p2;
                float4 xv = *(const float4*)(xb + (size_t)t * 1024);
                float xa[4] = {xv.x, xv.y, xv.z, xv.w};
#pragma unroll
                for (int j = 0; j < 4; j++) {
                    float e = __expf(acc[i][j][p2] - cm[j]);
                    ds[j] += e;
                    pm[j] += e * xa[j];
                }
            }
        }
#pragma unroll
        for (int j = 0; j < 4; j++) {
            ds[j] += __shfl_xor(ds[j], 16, 64);
            ds[j] += __shfl_xor(ds[j], 32, 64);
            pm[j] += __shfl_xor(pm[j], 16, 64);
            pm[j] += __shfl_xor(pm[j], 32, 64);
            if (qd == 0) {
                sred[wave * 64 + 16 * j + lx] = ds[j];
                pred[wave * 64 + 16 * j + lx] = pm[j];
            }
        }
        __syncthreads();
        if (tid < 64) {
            float dsum = sred[tid] + sred[64 + tid] + sred[128 + tid] + sred[192 + tid];
            float psum = pred[tid] + pred[64 + tid] + pred[128 + tid] + pred[192 + tid];
            const int u = u0 + 4 * (tid & 15) + (tid >> 4);  // un-permute
            m_out[(size_t)(r * 128 + b) * 1024 + u] = psum / dsum;
        }
        __syncthreads();  // LDS safe for next r (full drain)
    }
}

// ------- old k2 (fallback path): per-r dispatch ------------------------
__global__ __launch_bounds__(256) void k2_mfma(
    const unsigned short* __restrict__ Hh,
    const unsigned short* __restrict__ W2h,
    const float* __restrict__ x, float* __restrict__ m_out, int b0, int r) {
    __shared__ __align__(16) unsigned short Ah[256 * 32];
    __shared__ __align__(16) unsigned short Bh[64 * 32];
    __shared__ float mred[256], sred[256], pred[256];
    const int tid = threadIdx.x;
    const int b_local = blockIdx.x, b = b0 + b_local;
    const int u0 = blockIdx.y * 64;
    const int wave = tid >> 6, lane = tid & 63;
    const int lx = lane & 15, qd = lane >> 4;
    const int rl = lane >> 2, cl = (lane & 3) * 8;

    f32x4 acc[4][4];
#pragma unroll
    for (int i = 0; i < 4; i++)
#pragma unroll
        for (int j = 0; j < 4; j++) acc[i][j] = (f32x4){0.f, 0.f, 0.f, 0.f};

    const unsigned short* asrc = Hh + (size_t)(b_local * 256 + rl) * 512 + cl;
    const int ub = wave * 16 + rl;
    const unsigned short* bsrc =
        W2h + (size_t)(u0 + 4 * (ub & 15) + (ub >> 4)) * 512 + cl;

    for (int k0 = 0; k0 < 512; k0 += 32) {
#pragma unroll
        for (int s = 0; s < 4; s++) {
            const int c = wave * 4 + s;
            gll16(asrc + (size_t)c * 16 * 512 + k0, &Ah[c * 512]);
        }
        gll16(bsrc + k0, &Bh[wave * 512]);
        __syncthreads();
        bf16x8 fa[4], fb[4];
#pragma unroll
        for (int i = 0; i < 4; i++) {
            fa[i] = *(const bf16x8*)&Ah[(64 * wave + 16 * i + lx) * 32 + 8 * qd];
            fb[i] = *(const bf16x8*)&Bh[(16 * i + lx) * 32 + 8 * qd];
        }
#pragma unroll
        for (int i = 0; i < 4; i++)
#pragma unroll
            for (int j = 0; j < 4; j++)
                acc[i][j] = __builtin_amdgcn_mfma_f32_16x16x32_bf16(fa[i], fb[j], acc[i][j], 0, 0, 0);
        __syncthreads();
    }

    float cm[4];
#pragma unroll
    for (int j = 0; j < 4; j++) {
        float mx = acc[0][j][0];
#pragma unroll
        for (int i = 0; i < 4; i++)
#pragma unroll
            for (int p = 0; p < 4; p++) mx = fmaxf(mx, acc[i][j][p]);
        mx = fmaxf(mx, __shfl_xor(mx, 16, 64));
        mx = fmaxf(mx, __shfl_xor(mx, 32, 64));
        if (qd == 0) mred[wave * 64 + 16 * j + lx] = mx;
    }
    __syncthreads();
#pragma unroll
    for (int j = 0; j < 4; j++) {
        const int c = 16 * j + lx;
        cm[j] = fmaxf(fmaxf(mred[c], mred[64 + c]), fmaxf(mred[128 + c], mred[192 + c]));
    }

    float ds[4] = {0.f, 0.f, 0.f, 0.f}, pm[4] = {0.f, 0.f, 0.f, 0.f};
    const float* xb = x + (size_t)b * 256 * 1024 + u0 + 4 * lx;
#pragma unroll
    for (int i = 0; i < 4; i++) {
#pragma unroll
        for (int p = 0; p < 4; p++) {
            const int t = 64 * wave + 16 * i + 4 * qd + p;
            float4 xv = *(const float4*)(xb + (size_t)t * 1024);
            float xa[4] = {xv.x, xv.y, xv.z, xv.w};
#pragma unroll
            for (int j = 0; j < 4; j++) {
                float e = __expf(acc[i][j][p] - cm[j]);
                ds[j] += e;
                pm[j] += e * xa[j];
            }
        }
    }
#pragma unroll
    for (int j = 0; j < 4; j++) {
        ds[j] += __shfl_xor(ds[j], 16, 64);
        ds[j] += __shfl_xor(ds[j], 32, 64);
        pm[j] += __shfl_xor(pm[j], 16, 64);
        pm[j] += __shfl_xor(pm[j], 32, 64);
        if (qd == 0) {
            sred[wave * 64 + 16 * j + lx] = ds[j];
            pred[wave * 64 + 16 * j + lx] = pm[j];
        }
    }
    __syncthreads();
    if (tid < 64) {
        float dsum = sred[tid] + sred[64 + tid] + sred[128 + tid] + sred[192 + tid];
        float psum = pred[tid] + pred[64 + tid] + pred[128 + tid] + pred[192 + tid];
        const int u = u0 + 4 * (tid & 15) + (tid >> 4);
        m_out[(size_t)(r * 128 + b) * 1024 + u] = psum / dsum;
    }
}

// ------- k3 (MFMA): votes = m @ cw, cw split [r][n][k] hi/lo, 2-pass -------
__global__ __launch_bounds__(256) void k3_votes_mfma(
    const float* __restrict__ Mb,
    const unsigned short* __restrict__ CWh,
    const unsigned short* __restrict__ CWl,
    float* __restrict__ V) {
    __shared__ unsigned short Ah[128 * LDT];
    __shared__ unsigned short Bh[64 * LDT], Bl[64 * LDT];
    const int tid = threadIdx.x;
    const int r = blockIdx.x, n0 = blockIdx.y * 64;
    const int wave = tid >> 6, lane = tid & 63;
    const int wr = wave >> 1, wc = wave & 1;
    const int lx = lane & 15, qd = lane >> 4;
    const int srow = tid >> 1, scol = (tid & 1) * 16;
    const int brow = tid >> 2, bcol = (tid & 3) * 8;

    const float* arow = Mb + (size_t)(r * 128 + srow) * 1024 + scol;
    const unsigned short* bhrow = CWh + ((size_t)r * 2048 + n0 + brow) * 1024 + bcol;
    const unsigned short* blrow = CWl + ((size_t)r * 2048 + n0 + brow) * 1024 + bcol;

    f32x4 acc[4][2];
#pragma unroll
    for (int i = 0; i < 4; i++)
#pragma unroll
        for (int j = 0; j < 2; j++) acc[i][j] = (f32x4){0.f, 0.f, 0.f, 0.f};

    for (int k0 = 0; k0 < 1024; k0 += 32) {
        float4 v0 = *(const float4*)(arow + k0);
        float4 v1 = *(const float4*)(arow + k0 + 4);
        float4 v2 = *(const float4*)(arow + k0 + 8);
        float4 v3 = *(const float4*)(arow + k0 + 12);
        float vv[16] = {v0.x, v0.y, v0.z, v0.w, v1.x, v1.y, v1.z, v1.w,
                        v2.x, v2.y, v2.z, v2.w, v3.x, v3.y, v3.z, v3.w};
        u16x8 p0, p1;
#pragma unroll
        for (int e = 0; e < 8; e++) p0[e] = f2bf(vv[e]);
#pragma unroll
        for (int e = 0; e < 8; e++) p1[e] = f2bf(vv[8 + e]);
        *(u16x8*)&Ah[srow * LDT + scol] = p0;
        *(u16x8*)&Ah[srow * LDT + scol + 8] = p1;
        *(u16x8*)&Bh[brow * LDT + bcol] = *(const u16x8*)(bhrow + k0);
        *(u16x8*)&Bl[brow * LDT + bcol] = *(const u16x8*)(blrow + k0);
        __syncthreads();

        bf16x8 fa[4], fbh[2], fbl[2];
#pragma unroll
        for (int i = 0; i < 4; i++)
            fa[i] = *(const bf16x8*)&Ah[(64 * wr + 16 * i + lx) * LDT + 8 * qd];
#pragma unroll
        for (int j = 0; j < 2; j++) {
            fbh[j] = *(const bf16x8*)&Bh[(32 * wc + 16 * j + lx) * LDT + 8 * qd];
            fbl[j] = *(const bf16x8*)&Bl[(32 * wc + 16 * j + lx) * LDT + 8 * qd];
        }
#pragma unroll
        for (int i = 0; i < 4; i++)
#pragma unroll
            for (int j = 0; j < 2; j++)
                acc[i][j] = __builtin_amdgcn_mfma_f32_16x16x32_bf16(fa[i], fbh[j], acc[i][j], 0, 0, 0);
#pragma unroll
        for (int i = 0; i < 4; i++)
#pragma unroll
            for (int j = 0; j < 2; j++)
                acc[i][j] = __builtin_amdgcn_mfma_f32_16x16x32_bf16(fa[i], fbl[j], acc[i][j], 0, 0, 0);
        __syncthreads();
    }

#pragma unroll
    for (int i = 0; i < 4; i++)
#pragma unroll
        for (int j = 0; j < 2; j++) {
            const int col = n0 + 32 * wc + 16 * j + lx;
#pragma unroll
            for (int p = 0; p < 4; p++) {
                const int row = 64 * wr + 16 * i + 4 * qd + p;
                V[((size_t)r * 128 + row) * 2048 + col] = acc[i][j][p];
            }
        }
}

// ---------------- k3 fallback: fp32 VALU (small-ws path) ----------------
__global__ __launch_bounds__(256) void k3_votes(const float* __restrict__ Mb,
                                                const float* __restrict__ CW,
                                                float* __restrict__ V) {
    __shared__ float As[16][132];
    __shared__ float Bs[16][132];
    const int tid = threadIdx.x;
    const int r = blockIdx.z;
    const int n0 = blockIdx.x * 128;
    const float* A = Mb + (size_t)r * 128 * 1024;
    const float* Bm = CW + (size_t)r * 1024 * 2048;
    float* C = V + (size_t)r * 128 * 2048;
    const int ty = tid >> 4, tx = tid & 15;
    const int k4 = (tid & 3) * 4, row = tid >> 2;
    const int n4 = (tid & 31) * 4, krow = tid >> 5;

    float acc[8][8];
#pragma unroll
    for (int i = 0; i < 8; i++)
#pragma unroll
        for (int j = 0; j < 8; j++) acc[i][j] = 0.f;

    for (int k0 = 0; k0 < 1024; k0 += 16) {
#pragma unroll
        for (int rr = 0; rr < 2; rr++) {
            const int m = row + rr * 64;
            float4 av = *(const float4*)(A + (size_t)m * 1024 + k0 + k4);
            As[k4 + 0][m] = av.x; As[k4 + 1][m] = av.y;
            As[k4 + 2][m] = av.z; As[k4 + 3][m] = av.w;
            const int k = krow + rr * 8;
            float4 bv = *(const float4*)(Bm + (size_t)(k0 + k) * 2048 + n0 + n4);
            *(float4*)(&Bs[k][n4]) = bv;
        }
        __syncthreads();
#pragma unroll
        for (int k = 0; k < 16; k++) {
            float a[8], b[8];
            *(float4*)(a)     = *(const float4*)(&As[k][ty * 8]);
            *(float4*)(a + 4) = *(const float4*)(&As[k][ty * 8 + 4]);
            *(float4*)(b)     = *(const float4*)(&Bs[k][tx * 8]);
            *(float4*)(b + 4) = *(const float4*)(&Bs[k][tx * 8 + 4]);
#pragma unroll
            for (int i = 0; i < 8; i++)
#pragma unroll
                for (int j = 0; j < 8; j++) acc[i][j] += a[i] * b[j];
        }
        __syncthreads();
    }
#pragma unroll
    for (int i = 0; i < 8; i++) {
        const int m = ty * 8 + i;
#pragma unroll
        for (int j = 0; j < 8; j += 4) {
            float4 v;
            v.x = acc[i][j + 0]; v.y = acc[i][j + 1];
            v.z = acc[i][j + 2]; v.w = acc[i][j + 3];
            *(float4*)(C + (size_t)m * 2048 + n0 + tx * 8 + j) = v;
        }
    }
}

// ---------------- k4: dynamic routing ----------------
__global__ __launch_bounds__(256) void k4_routing(const float* __restrict__ V,
                                                  float* __restrict__ out) {
    __shared__ float logits[8 * 128];
    __shared__ float route[8 * 128];
    __shared__ float preact[128 * 16];
    __shared__ float act[128 * 16];
    __shared__ float fred[128];
    const int b = blockIdx.x, tid = threadIdx.x;
    const float* vb = V + (size_t)b * 2048;

    for (int i = tid; i < 1024; i += 256) logits[i] = 0.f;
    __syncthreads();

    for (int it = 0; it < 3; it++) {
        {
            const int r = tid >> 5, g = tid & 31;
            float l[4];
#pragma unroll
            for (int q = 0; q < 4; q++) l[q] = logits[r * 128 + g + q * 32];
            float mx = fmaxf(fmaxf(l[0], l[1]), fmaxf(l[2], l[3]));
            for (int msk = 16; msk; msk >>= 1) mx = fmaxf(mx, __shfl_xor(mx, msk, 32));
            float e[4], s = 0.f;
#pragma unroll
            for (int q = 0; q < 4; q++) { e[q] = expf(l[q] - mx); s += e[q]; }
            for (int msk = 16; msk; msk >>= 1) s += __shfl_xor(s, msk, 32);
            float inv = 1.f / s;
#pragma unroll
            for (int q = 0; q < 4; q++) route[r * 128 + g + q * 32] = e[q] * inv;
        }
        __syncthreads();
        for (int i = tid; i < 2048; i += 256) {
            const int c = i >> 4;
            float a = 0.f;
#pragma unroll
            for (int r = 0; r < 8; r++)
                a += route[r * 128 + c] * vb[(size_t)r * 128 * 2048 + i];
            preact[i] = a;
        }
        __syncthreads();
        if (tid < 128) {
            float n2 = 0.f;
#pragma unroll
            for (int o = 0; o < 16; o++) { float p = preact[tid * 16 + o]; n2 += p * p; }
            fred[tid] = sqrtf(n2) / (1.f + n2);
        }
        __syncthreads();
        for (int i = tid; i < 2048; i += 256) act[i] = preact[i] * fred[i >> 4];
        __syncthreads();
        for (int i = tid; i < 1024; i += 256) {
            const int r = i >> 7, c = i & 127;
            float d = 0.f;
#pragma unroll
            for (int o = 0; o < 16; o++)
                d += vb[(size_t)r * 128 * 2048 + c * 16 + o] * act[c * 16 + o];
            logits[i] += d;
        }
        __syncthreads();
    }
    if (tid < 128) {
        float n2 = 0.f;
#pragma unroll
        for (int o = 0; o < 16; o++) { float a = act[tid * 16 + o]; n2 += a * a; }
        out[(size_t)b * 128 + tid] = sqrtf(n2);
    }
}

extern "C" void kernel_launch(void* const* d_in, const int* in_sizes, int n_in,
                              void* d_out, int out_size, void* d_ws, size_t ws_size,
                              hipStream_t stream) {
    const float* x   = (const float*)d_in[0];
    const float* WS1 = (const float*)d_in[1];
    const float* WS2 = (const float*)d_in[2];
    const float* cw  = (const float*)d_in[3];
    float* out = (float*)d_out;

    char* ws = (char*)d_ws;
    float* m_buf = (float*)ws;                                      // 4 MiB
    float* votes = (float*)(ws + ((size_t)4 << 20));                // 8 MiB
    unsigned short* W1h = (unsigned short*)(ws + ((size_t)12 << 20)); // 8 MiB
    unsigned short* W2h = (unsigned short*)(ws + ((size_t)20 << 20)); // 8 MiB

    const bool use_cw  = ws_size >= ((size_t)124 << 20);
    const bool use_xbf = ws_size >= ((size_t)188 << 20);

    const int nW4 = (8 * 512 * 1024) / 4;
    k0_hi<<<dim3((nW4 + 255) / 256), dim3(256), 0, stream>>>(WS1, W1h, nW4);
    k0_hi<<<dim3((nW4 + 255) / 256), dim3(256), 0, stream>>>(WS2, W2h, nW4);

    if (use_xbf) {
        // --- big-ws path: Xbf @28, HhA @92 (overlaid by CWh/CWl post-loop) ---
        unsigned short* Xbf = (unsigned short*)(ws + ((size_t)28 << 20)); // 64 MiB
        unsigned short* HhA = (unsigned short*)(ws + ((size_t)92 << 20)); // 64 MiB
        unsigned short* CWh = (unsigned short*)(ws + ((size_t)92 << 20)); // 32 MiB
        unsigned short* CWl = (unsigned short*)(ws + ((size_t)124 << 20)); // 32 MiB

        const int nX4 = (128 * 256 * 1024) / 4;
        k0_hi<<<dim3((nX4 + 255) / 256), dim3(256), 0, stream>>>(x, Xbf, nX4);

        for (int b0 = 0; b0 < 128; b0 += 32) {
            k1_all<<<dim3(64, 4, 8), dim3(256), 0, stream>>>(
                Xbf + (size_t)b0 * 256 * 1024, W1h, HhA);
            k2_allr<<<dim3(32, 16, 2), dim3(256), 0, stream>>>(
                HhA, W2h, x, m_buf, b0);
        }
        // HhA dead; overlay CWh/CWl and finish
        k0_tsplit<<<dim3(32, 16, 8), dim3(256), 0, stream>>>(cw, CWh, CWl);
        k3_votes_mfma<<<dim3(8, 32), dim3(256), 0, stream>>>(m_buf, CWh, CWl, votes);
    } else {
        // --- fallback path: round-4/5 flow ---
        unsigned short* CWh = (unsigned short*)(ws + ((size_t)28 << 20));
        unsigned short* CWl = (unsigned short*)(ws + ((size_t)60 << 20));
        const size_t hh_off = use_cw ? ((size_t)92 << 20) : ((size_t)28 << 20);
        unsigned short* Hh = (unsigned short*)(ws + hh_off);

        int CB = 128;
        {
            const size_t perb = (size_t)256 << 10;
            if (ws_size < hh_off + 128 * perb) {
                size_t avail = (ws_size > hh_off) ? (ws_size - hh_off) : perb;
                CB = (int)(avail / perb);
                if (CB < 1) CB = 1;
                if (CB > 128) CB = 128;
            }
        }

        if (use_cw)
            k0_tsplit<<<dim3(32, 16, 8), dim3(256), 0, stream>>>(cw, CWh, CWl);

        for (int b0 = 0; b0 < 128; b0 += CB) {
            const int bc = (128 - b0 < CB) ? (128 - b0) : CB;
            for (int r = 0; r < 8; r++) {
                k1_hbar_mfma<0><<<dim3(bc * 2, 4), dim3(256), 0, stream>>>(
                    (const void*)(x + (size_t)b0 * 256 * 1024),
                    W1h + (size_t)r * 512 * 1024, Hh);
                k2_mfma<<<dim3(bc, 16), dim3(256), 0, stream>>>(
                    Hh, W2h + (size_t)r * 1024 * 512, x, m_buf, b0, r);
            }
        }
        if (use_cw)
            k3_votes_mfma<<<dim3(8, 32), dim3(256), 0, stream>>>(m_buf, CWh, CWl, votes);
        else
            k3_votes<<<dim3(16, 1, 8), dim3(256), 0, stream>>>(m_buf, cw, votes);
    }
    k4_routing<<<dim3(128), dim3(256), 0, stream>>>(votes, out);
}

// Round 4
// 1544.562 us; speedup vs baseline: 1.0941x; 1.0941x over previous
//
#include <hip/hip_runtime.h>

// CapsAll on MI355X — round 8: barrier-free fragment-direct GEMMs.
// Round-7 post-mortem: 3-buf counted pipeline halved occupancy (LDS 63KB,
// VGPR 176) -> regression. Root structural problem: LDS staging + barrier
// per K-step on small L2-hot tiles. Fix: pre-transform operands into MFMA
// fragment tiles (1KB = 64 lanes x 16B), load fragments global->VGPR
// coalesced, register double-buffer, ZERO barriers in the K-loop.
//
//   k0_w1frag/k0_w2frag/k0_xfrag: fp32 -> bf16 fragment-tile layout
//   k0_tsplit: cw -> [r][n][k] bf16 hi+lo (unchanged)
//   k1_frag: hbar = relu(X @ W1_r^T), frag-direct, writes Hh in frag layout
//   k2_frag: scores GEMM + col-softmax + m, 4 r per block, frag-direct
//            (u-permutation baked into W2frag -> coalesced float4 x loads)
//   k3:  votes = m @ cw, 2-pass MFMA (fallback: fp32 VALU kernel)
//   k4:  dynamic routing (3 iters) + norms
//
// Numerics: identical MFMA sequence/order vs round 6 (absmax ~4.8e-7).
//
// ws layout, big path (>=188 MB): m 4 @0 | votes 8 @4 | W1f 8 @12 |
//   W2f 8 @20 | Xf 64 @28 | Hf 64 @92 (overlaid post-loop by CWh/CWl).

typedef __attribute__((ext_vector_type(8))) short bf16x8;
typedef __attribute__((ext_vector_type(8))) unsigned short u16x8;
typedef __attribute__((ext_vector_type(4))) float f32x4;

#define LDT 40  // LDS row stride (bf16) for the legacy reg-staged kernels

__device__ __forceinline__ unsigned short f2bf(float f) {
    unsigned u = __float_as_uint(f);
    u += 0x7FFF + ((u >> 16) & 1);           // round-to-nearest-even
    return (unsigned short)(u >> 16);
}
__device__ __forceinline__ float bf2f(unsigned short h) {
    return __uint_as_float(((unsigned)h) << 16);
}

// async global->LDS (fallback kernels only)
typedef __attribute__((address_space(1))) void gvoid;
typedef __attribute__((address_space(3))) void lvoid;
__device__ __forceinline__ void gll16(const unsigned short* g, unsigned short* l) {
    __builtin_amdgcn_global_load_lds((gvoid*)g, (lvoid*)l, 16, 0, 0);
}

// ---------------- k0h: elementwise fp32 -> bf16 hi plane (fallback) -----
__global__ __launch_bounds__(256) void k0_hi(const float* __restrict__ src,
                                             unsigned short* __restrict__ hi,
                                             int n4) {
    int i = blockIdx.x * 256 + threadIdx.x;
    if (i >= n4) return;
    float4 v = ((const float4*)src)[i];
    ushort4 h;
    h.x = f2bf(v.x); h.y = f2bf(v.y); h.z = f2bf(v.z); h.w = f2bf(v.w);
    ((ushort4*)hi)[i] = h;
}

// ---- k0_xfrag: x [32768][1024] fp32 -> Xf[2048 tb][32 kb][512] bf16 ----
// Fragment tile semantics: ushort idx (tb*32+kb)*512 + lane*8 + e equals
// X[tb*16 + (lane&15)][kb*32 + (lane>>4)*8 + e].
__global__ __launch_bounds__(256) void k0_xfrag(const float* __restrict__ x,
                                                unsigned short* __restrict__ Xf) {
    const int tid = threadIdx.x;
    const int tb = blockIdx.x;
    const int kb = blockIdx.y * 4 + (tid >> 6);
    const int lane = tid & 63, lx = lane & 15, qd = lane >> 4;
    const float* src = x + (size_t)(tb * 16 + lx) * 1024 + kb * 32 + qd * 8;
    float4 v0 = *(const float4*)(src);
    float4 v1 = *(const float4*)(src + 4);
    u16x8 o;
    o[0] = f2bf(v0.x); o[1] = f2bf(v0.y); o[2] = f2bf(v0.z); o[3] = f2bf(v0.w);
    o[4] = f2bf(v1.x); o[5] = f2bf(v1.y); o[6] = f2bf(v1.z); o[7] = f2bf(v1.w);
    *(u16x8*)(Xf + ((size_t)(tb * 32 + kb) * 512) + lane * 8) = o;
}

// ---- k0_w1frag: WS1 [r][512 n][1024 k] -> W1f[r][32 nb][32 kb][512] ----
__global__ __launch_bounds__(256) void k0_w1frag(const float* __restrict__ W1,
                                                 unsigned short* __restrict__ Wf) {
    const int tid = threadIdx.x;
    const int nb = blockIdx.x, r = blockIdx.z;
    const int kb = blockIdx.y * 4 + (tid >> 6);
    const int lane = tid & 63, lx = lane & 15, qd = lane >> 4;
    const float* src = W1 + (size_t)r * 512 * 1024 +
                       (size_t)(nb * 16 + lx) * 1024 + kb * 32 + qd * 8;
    float4 v0 = *(const float4*)(src);
    float4 v1 = *(const float4*)(src + 4);
    u16x8 o;
    o[0] = f2bf(v0.x); o[1] = f2bf(v0.y); o[2] = f2bf(v0.z); o[3] = f2bf(v0.w);
    o[4] = f2bf(v1.x); o[5] = f2bf(v1.y); o[6] = f2bf(v1.z); o[7] = f2bf(v1.w);
    *(u16x8*)(Wf + ((size_t)((r * 32 + nb) * 32 + kb) * 512) + lane * 8) = o;
}

// ---- k0_w2frag: WS2 [r][1024 u][512 k] -> W2f[r][16 ub][4 j][16 kb][512]
// with the u-permutation baked in: tile (ub,j), lane lx <-> u = ub*64+4*lx+j.
__global__ __launch_bounds__(256) void k0_w2frag(const float* __restrict__ W2,
                                                 unsigned short* __restrict__ Wf) {
    const int tid = threadIdx.x;
    const int ub = blockIdx.x, kb = blockIdx.y, r = blockIdx.z;
    const int j = tid >> 6, lane = tid & 63, lx = lane & 15, qd = lane >> 4;
    const float* src = W2 + (size_t)r * 1024 * 512 +
                       (size_t)(ub * 64 + 4 * lx + j) * 512 + kb * 32 + qd * 8;
    float4 v0 = *(const float4*)(src);
    float4 v1 = *(const float4*)(src + 4);
    u16x8 o;
    o[0] = f2bf(v0.x); o[1] = f2bf(v0.y); o[2] = f2bf(v0.z); o[3] = f2bf(v0.w);
    o[4] = f2bf(v1.x); o[5] = f2bf(v1.y); o[6] = f2bf(v1.z); o[7] = f2bf(v1.w);
    *(u16x8*)(Wf + ((size_t)(((r * 16 + ub) * 4 + j) * 16 + kb) * 512) + lane * 8) = o;
}

// ------- k0t: cw [r][k=1024][n=2048] fp32 -> [r][n][k] bf16 hi+lo -------
__global__ __launch_bounds__(256) void k0_tsplit(const float* __restrict__ cw,
                                                 unsigned short* __restrict__ ch,
                                                 unsigned short* __restrict__ cl) {
    __shared__ unsigned short Th[64 * 68], Tl[64 * 68];
    const int tid = threadIdx.x;
    const int n0 = blockIdx.x * 64, k0 = blockIdx.y * 64, r = blockIdx.z;
    const float* src = cw + (size_t)r * 1024 * 2048;
#pragma unroll
    for (int p = 0; p < 4; p++) {
        const int kl = p * 16 + (tid >> 4);
        const int nl = (tid & 15) * 4;
        float4 v = *(const float4*)(src + (size_t)(k0 + kl) * 2048 + n0 + nl);
        float vv[4] = {v.x, v.y, v.z, v.w};
#pragma unroll
        for (int e = 0; e < 4; e++) {
            unsigned short h = f2bf(vv[e]);
            Th[(nl + e) * 68 + kl] = h;
            Tl[(nl + e) * 68 + kl] = f2bf(vv[e] - bf2f(h));
        }
    }
    __syncthreads();
    const int nl = tid >> 2, kl = (tid & 3) * 16;
    unsigned short* dh = ch + ((size_t)r * 2048 + n0 + nl) * 1024 + k0 + kl;
    unsigned short* dl = cl + ((size_t)r * 2048 + n0 + nl) * 1024 + k0 + kl;
    *(u16x8*)(dh)     = *(const u16x8*)&Th[nl * 68 + kl];
    *(u16x8*)(dh + 8) = *(const u16x8*)&Th[nl * 68 + kl + 8];
    *(u16x8*)(dl)     = *(const u16x8*)&Tl[nl * 68 + kl];
    *(u16x8*)(dl + 8) = *(const u16x8*)&Tl[nl * 68 + kl + 8];
}

#define LDF(P, OFF) (*(const bf16x8*)((P) + (OFF)))

// -------- k1_frag: hbar = relu(X @ W1_r^T), barrier-free frag-direct ----
// 128x128 tile, 4 waves (2x2 of 64x64), NT=32 K-steps, reg double-buffer.
// grid (64 m, 4 n, 8 r): id%8 = m%8 -> X slice L2-hot across (n,r).
__global__ __launch_bounds__(256, 3) void k1_frag(
    const unsigned short* __restrict__ Xf,   // chunk base, frag layout
    const unsigned short* __restrict__ W1f,  // [8][32][32][512]
    unsigned short* __restrict__ HfA) {      // [8][512 tb][16 kb][512]
    const int tid = threadIdx.x;
    const int bx = blockIdx.x, n0 = blockIdx.y * 128, r = blockIdx.z;
    const int wave = tid >> 6, lane = tid & 63;
    const int wm = (wave >> 1) * 64, wn = (wave & 1) * 64;
    const int lx = lane & 15, qd = lane >> 4;
    const size_t l8 = (size_t)lane * 8;

    f32x4 acc[4][4];
#pragma unroll
    for (int i = 0; i < 4; i++)
#pragma unroll
        for (int j = 0; j < 4; j++) acc[i][j] = (f32x4){0.f, 0.f, 0.f, 0.f};

    const unsigned short* ab[4];
    const unsigned short* bb[4];
#pragma unroll
    for (int i = 0; i < 4; i++) {
        ab[i] = Xf + ((size_t)(bx * 8 + (wm >> 4) + i) * 32) * 512 + l8;
        bb[i] = W1f + ((size_t)(r * 32 + ((n0 + wn) >> 4) + i) * 32) * 512 + l8;
    }

    bf16x8 fa0[4], fb0[4], fa1[4], fb1[4];
#pragma unroll
    for (int i = 0; i < 4; i++) { fa0[i] = LDF(ab[i], 0); fb0[i] = LDF(bb[i], 0); }
    for (int t = 0; t < 32; t += 2) {
#pragma unroll
        for (int i = 0; i < 4; i++) { fa1[i] = LDF(ab[i], 512); fb1[i] = LDF(bb[i], 512); }
#pragma unroll
        for (int i = 0; i < 4; i++)
#pragma unroll
            for (int j = 0; j < 4; j++)
                acc[i][j] = __builtin_amdgcn_mfma_f32_16x16x32_bf16(fa0[i], fb0[j], acc[i][j], 0, 0, 0);
        if (t + 2 < 32) {
#pragma unroll
            for (int i = 0; i < 4; i++) {
                ab[i] += 1024; bb[i] += 1024;
                fa0[i] = LDF(ab[i], 0); fb0[i] = LDF(bb[i], 0);
            }
        }
#pragma unroll
        for (int i = 0; i < 4; i++)
#pragma unroll
            for (int j = 0; j < 4; j++)
                acc[i][j] = __builtin_amdgcn_mfma_f32_16x16x32_bf16(fa1[i], fb1[j], acc[i][j], 0, 0, 0);
    }

    // epilogue: relu + write Hh in fragment layout.
    // element (t=m0+wm+16i+4qd+p, k=n0+wn+16j+lx):
    //   tb=(m0+wm)/16+i, kb=(n0+wn)/32+(j>>1), qd'=2(j&1)+(lx>>3),
    //   lx'=4qd+p, e'=lx&7
    unsigned short* H = HfA + (size_t)r * 4194304;
    const int tb0 = bx * 8 + (wm >> 4);
    const int kb0 = (n0 + wn) >> 5;
#pragma unroll
    for (int i = 0; i < 4; i++)
#pragma unroll
        for (int j = 0; j < 4; j++) {
            const int qd2 = 2 * (j & 1) + (lx >> 3);
            const size_t base =
                ((size_t)((tb0 + i) * 16 + kb0 + (j >> 1)) * 512) +
                (qd2 * 16 + 4 * qd) * 8 + (lx & 7);
#pragma unroll
            for (int p = 0; p < 4; p++)
                H[base + p * 8] = f2bf(fmaxf(acc[i][j][p], 0.f));
        }
}

// ------- k2_frag: scores GEMM + col-softmax + m, 4 r per block ----------
// grid (32 b, 16 u, 2 r-halves). Barrier-free K-loop (NT=16), reg dbuf.
// x slice L2-hot across the 4-r loop; u-permutation baked in W2f.
__global__ __launch_bounds__(256, 3) void k2_frag(
    const unsigned short* __restrict__ Hf,    // [8][512 tb][16 kb][512] chunk
    const unsigned short* __restrict__ W2f,   // [8][16][4][16][512]
    const float* __restrict__ x, float* __restrict__ m_out, int b0) {
    __shared__ float mred[256], sred[256], pred[256];
    const int tid = threadIdx.x;
    const int b_local = blockIdx.x, b = b0 + b_local;
    const int u0 = blockIdx.y * 64;
    const int r_base = blockIdx.z * 4;
    const int wave = tid >> 6, lane = tid & 63;
    const int lx = lane & 15, qd = lane >> 4;
    const size_t l8 = (size_t)lane * 8;

    for (int rr = 0; rr < 4; ++rr) {
        const int r = r_base + rr;
        const unsigned short* ab[4];
        const unsigned short* bb[4];
#pragma unroll
        for (int i = 0; i < 4; i++) {
            ab[i] = Hf + (size_t)r * 4194304 +
                    ((size_t)(b_local * 16 + wave * 4 + i) * 16) * 512 + l8;
            bb[i] = W2f + ((size_t)(((r * 16 + blockIdx.y) * 4 + i) * 16)) * 512 + l8;
        }

        f32x4 acc[4][4];
#pragma unroll
        for (int i = 0; i < 4; i++)
#pragma unroll
            for (int j = 0; j < 4; j++) acc[i][j] = (f32x4){0.f, 0.f, 0.f, 0.f};

        bf16x8 fa0[4], fb0[4], fa1[4], fb1[4];
#pragma unroll
        for (int i = 0; i < 4; i++) { fa0[i] = LDF(ab[i], 0); fb0[i] = LDF(bb[i], 0); }
        for (int t = 0; t < 16; t += 2) {
#pragma unroll
            for (int i = 0; i < 4; i++) { fa1[i] = LDF(ab[i], 512); fb1[i] = LDF(bb[i], 512); }
#pragma unroll
            for (int i = 0; i < 4; i++)
#pragma unroll
                for (int j = 0; j < 4; j++)
                    acc[i][j] = __builtin_amdgcn_mfma_f32_16x16x32_bf16(fa0[i], fb0[j], acc[i][j], 0, 0, 0);
            if (t + 2 < 16) {
#pragma unroll
                for (int i = 0; i < 4; i++) {
                    ab[i] += 1024; bb[i] += 1024;
                    fa0[i] = LDF(ab[i], 0); fb0[i] = LDF(bb[i], 0);
                }
            }
#pragma unroll
            for (int i = 0; i < 4; i++)
#pragma unroll
                for (int j = 0; j < 4; j++)
                    acc[i][j] = __builtin_amdgcn_mfma_f32_16x16x32_bf16(fa1[i], fb1[j], acc[i][j], 0, 0, 0);
        }

        // ---- column max over t: per-lane -> cross-quad -> cross-wave ----
        float cm[4];
#pragma unroll
        for (int j = 0; j < 4; j++) {
            float mx = acc[0][j][0];
#pragma unroll
            for (int i = 0; i < 4; i++)
#pragma unroll
                for (int p2 = 0; p2 < 4; p2++) mx = fmaxf(mx, acc[i][j][p2]);
            mx = fmaxf(mx, __shfl_xor(mx, 16, 64));
            mx = fmaxf(mx, __shfl_xor(mx, 32, 64));
            if (qd == 0) mred[wave * 64 + 16 * j + lx] = mx;
        }
        __syncthreads();
#pragma unroll
        for (int j = 0; j < 4; j++) {
            const int c = 16 * j + lx;
            cm[j] = fmaxf(fmaxf(mred[c], mred[64 + c]),
                          fmaxf(mred[128 + c], mred[192 + c]));
        }

        // ---- exp + weighted sum against x (float4 coalesced, L2-hot) ----
        float ds[4] = {0.f, 0.f, 0.f, 0.f}, pm[4] = {0.f, 0.f, 0.f, 0.f};
        const float* xb = x + (size_t)b * 256 * 1024 + u0 + 4 * lx;
#pragma unroll
        for (int i = 0; i < 4; i++) {
#pragma unroll
            for (int p2 = 0; p2 < 4; p2++) {
                const int t = 64 * wave + 16 * i + 4 * qd + p2;
                float4 xv = *(const float4*)(xb + (size_t)t * 1024);
                float xa[4] = {xv.x, xv.y, xv.z, xv.w};
#pragma unroll
                for (int j = 0; j < 4; j++) {
                    float e = __expf(acc[i][j][p2] - cm[j]);
                    ds[j] += e;
                    pm[j] += e * xa[j];
                }
            }
        }
#pragma unroll
        for (int j = 0; j < 4; j++) {
            ds[j] += __shfl_xor(ds[j], 16, 64);
            ds[j] += __shfl_xor(ds[j], 32, 64);
            pm[j] += __shfl_xor(pm[j], 16, 64);
            pm[j] += __shfl_xor(pm[j], 32, 64);
            if (qd == 0) {
                sred[wave * 64 + 16 * j + lx] = ds[j];
                pred[wave * 64 + 16 * j + lx] = pm[j];
            }
        }
        __syncthreads();
        if (tid < 64) {
            float dsum = sred[tid] + sred[64 + tid] + sred[128 + tid] + sred[192 + tid];
            float psum = pred[tid] + pred[64 + tid] + pred[128 + tid] + pred[192 + tid];
            const int u = u0 + 4 * (tid & 15) + (tid >> 4);  // un-permute
            m_out[(size_t)(r * 128 + b) * 1024 + u] = psum / dsum;
        }
        __syncthreads();  // LDS safe for next r
    }
}

// ---- k1 fallback (fp32 x, reg-staged): round-4 kernel ------------------
template <int XBF>
__global__ __launch_bounds__(256) void k1_hbar_mfma(
    const void* __restrict__ Xv,
    const unsigned short* __restrict__ Wh,
    unsigned short* __restrict__ Hh) {
    __shared__ unsigned short Ah[128 * LDT];
    __shared__ unsigned short Bh[128 * LDT];
    const int tid = threadIdx.x;
    const int m0 = blockIdx.x * 128, n0 = blockIdx.y * 128;
    const int wave = tid >> 6, lane = tid & 63;
    const int wm = (wave >> 1) * 64, wn = (wave & 1) * 64;
    const int lx = lane & 15, qd = lane >> 4;
    const int srow = tid >> 1, scol = (tid & 1) * 16;

    f32x4 acc[4][4];
#pragma unroll
    for (int i = 0; i < 4; i++)
#pragma unroll
        for (int j = 0; j < 4; j++) acc[i][j] = (f32x4){0.f, 0.f, 0.f, 0.f};

    const unsigned short* whrow = Wh + (size_t)(n0 + srow) * 1024 + scol;
    unsigned short* ah = &Ah[srow * LDT + scol];
    unsigned short* bh = &Bh[srow * LDT + scol];

    for (int k0 = 0; k0 < 1024; k0 += 32) {
        if (XBF) {
            const unsigned short* xrow =
                (const unsigned short*)Xv + (size_t)(m0 + srow) * 1024 + scol;
            u16x8 a0 = *(const u16x8*)(xrow + k0);
            u16x8 a1 = *(const u16x8*)(xrow + k0 + 8);
            *(u16x8*)(ah) = a0; *(u16x8*)(ah + 8) = a1;
        } else {
            const float* xrow = (const float*)Xv + (size_t)(m0 + srow) * 1024 + scol;
            float4 v0 = *(const float4*)(xrow + k0);
            float4 v1 = *(const float4*)(xrow + k0 + 4);
            float4 v2 = *(const float4*)(xrow + k0 + 8);
            float4 v3 = *(const float4*)(xrow + k0 + 12);
            float vv[16] = {v0.x, v0.y, v0.z, v0.w, v1.x, v1.y, v1.z, v1.w,
                            v2.x, v2.y, v2.z, v2.w, v3.x, v3.y, v3.z, v3.w};
            u16x8 p0, p1;
#pragma unroll
            for (int e = 0; e < 8; e++) p0[e] = f2bf(vv[e]);
#pragma unroll
            for (int e = 0; e < 8; e++) p1[e] = f2bf(vv[8 + e]);
            *(u16x8*)(ah) = p0; *(u16x8*)(ah + 8) = p1;
        }
        u16x8 b0 = *(const u16x8*)(whrow + k0);
        u16x8 b1 = *(const u16x8*)(whrow + k0 + 8);
        *(u16x8*)(bh) = b0; *(u16x8*)(bh + 8) = b1;
        __syncthreads();

        bf16x8 fa[4], fb[4];
#pragma unroll
        for (int i = 0; i < 4; i++) {
            fa[i] = *(const bf16x8*)&Ah[(wm + 16 * i + lx) * LDT + 8 * qd];
            fb[i] = *(const bf16x8*)&Bh[(wn + 16 * i + lx) * LDT + 8 * qd];
        }
#pragma unroll
        for (int i = 0; i < 4; i++)
#pragma unroll
            for (int j = 0; j < 4; j++)
                acc[i][j] = __builtin_amdgcn_mfma_f32_16x16x32_bf16(fa[i], fb[j], acc[i][j], 0, 0, 0);
        __syncthreads();
    }

#pragma unroll
    for (int i = 0; i < 4; i++)
#pragma unroll
        for (int j = 0; j < 4; j++) {
            const int col = n0 + wn + 16 * j + lx;
#pragma unroll
            for (int p = 0; p < 4; p++) {
                const int row = m0 + wm + 16 * i + 4 * qd + p;
                Hh[(size_t)row * 512 + col] = f2bf(fmaxf(acc[i][j][p], 0.f));
            }
        }
}

// ------- k2 fallback: per-r dispatch, gll16 + syncthreads ---------------
__global__ __launch_bounds__(256) void k2_mfma(
    const unsigned short* __restrict__ Hh,
    const unsigned short* __restrict__ W2h,
    const float* __restrict__ x, float* __restrict__ m_out, int b0, int r) {
    __shared__ __align__(16) unsigned short Ah[256 * 32];
    __shared__ __align__(16) unsigned short Bh[64 * 32];
    __shared__ float mred[256], sred[256], pred[256];
    const int tid = threadIdx.x;
    const int b_local = blockIdx.x, b = b0 + b_local;
    const int u0 = blockIdx.y * 64;
    const int wave = tid >> 6, lane = tid & 63;
    const int lx = lane & 15, qd = lane >> 4;
    const int rl = lane >> 2, cl = (lane & 3) * 8;

    f32x4 acc[4][4];
#pragma unroll
    for (int i = 0; i < 4; i++)
#pragma unroll
        for (int j = 0; j < 4; j++) acc[i][j] = (f32x4){0.f, 0.f, 0.f, 0.f};

    const unsigned short* asrc = Hh + (size_t)(b_local * 256 + rl) * 512 + cl;
    const int ub = wave * 16 + rl;
    const unsigned short* bsrc =
        W2h + (size_t)(u0 + 4 * (ub & 15) + (ub >> 4)) * 512 + cl;

    for (int k0 = 0; k0 < 512; k0 += 32) {
#pragma unroll
        for (int s = 0; s < 4; s++) {
            const int c = wave * 4 + s;
            gll16(asrc + (size_t)c * 16 * 512 + k0, &Ah[c * 512]);
        }
        gll16(bsrc + k0, &Bh[wave * 512]);
        __syncthreads();
        bf16x8 fa[4], fb[4];
#pragma unroll
        for (int i = 0; i < 4; i++) {
            fa[i] = *(const bf16x8*)&Ah[(64 * wave + 16 * i + lx) * 32 + 8 * qd];
            fb[i] = *(const bf16x8*)&Bh[(16 * i + lx) * 32 + 8 * qd];
        }
#pragma unroll
        for (int i = 0; i < 4; i++)
#pragma unroll
            for (int j = 0; j < 4; j++)
                acc[i][j] = __builtin_amdgcn_mfma_f32_16x16x32_bf16(fa[i], fb[j], acc[i][j], 0, 0, 0);
        __syncthreads();
    }

    float cm[4];
#pragma unroll
    for (int j = 0; j < 4; j++) {
        float mx = acc[0][j][0];
#pragma unroll
        for (int i = 0; i < 4; i++)
#pragma unroll
            for (int p = 0; p < 4; p++) mx = fmaxf(mx, acc[i][j][p]);
        mx = fmaxf(mx, __shfl_xor(mx, 16, 64));
        mx = fmaxf(mx, __shfl_xor(mx, 32, 64));
        if (qd == 0) mred[wave * 64 + 16 * j + lx] = mx;
    }
    __syncthreads();
#pragma unroll
    for (int j = 0; j < 4; j++) {
        const int c = 16 * j + lx;
        cm[j] = fmaxf(fmaxf(mred[c], mred[64 + c]), fmaxf(mred[128 + c], mred[192 + c]));
    }

    float ds[4] = {0.f, 0.f, 0.f, 0.f}, pm[4] = {0.f, 0.f, 0.f, 0.f};
    const float* xb = x + (size_t)b * 256 * 1024 + u0 + 4 * lx;
#pragma unroll
    for (int i = 0; i < 4; i++) {
#pragma unroll
        for (int p = 0; p < 4; p++) {
            const int t = 64 * wave + 16 * i + 4 * qd + p;
            float4 xv = *(const float4*)(xb + (size_t)t * 1024);
            float xa[4] = {xv.x, xv.y, xv.z, xv.w};
#pragma unroll
            for (int j = 0; j < 4; j++) {
                float e = __expf(acc[i][j][p] - cm[j]);
                ds[j] += e;
                pm[j] += e * xa[j];
            }
        }
    }
#pragma unroll
    for (int j = 0; j < 4; j++) {
        ds[j] += __shfl_xor(ds[j], 16, 64);
        ds[j] += __shfl_xor(ds[j], 32, 64);
        pm[j] += __shfl_xor(pm[j], 16, 64);
        pm[j] += __shfl_xor(pm[j], 32, 64);
        if (qd == 0) {
            sred[wave * 64 + 16 * j + lx] = ds[j];
            pred[wave * 64 + 16 * j + lx] = pm[j];
        }
    }
    __syncthreads();
    if (tid < 64) {
        float dsum = sred[tid] + sred[64 + tid] + sred[128 + tid] + sred[192 + tid];
        float psum = pred[tid] + pred[64 + tid] + pred[128 + tid] + pred[192 + tid];
        const int u = u0 + 4 * (tid & 15) + (tid >> 4);
        m_out[(size_t)(r * 128 + b) * 1024 + u] = psum / dsum;
    }
}

// ------- k3 (MFMA): votes = m @ cw, cw split [r][n][k] hi/lo, 2-pass -------
__global__ __launch_bounds__(256) void k3_votes_mfma(
    const float* __restrict__ Mb,
    const unsigned short* __restrict__ CWh,
    const unsigned short* __restrict__ CWl,
    float* __restrict__ V) {
    __shared__ unsigned short Ah[128 * LDT];
    __shared__ unsigned short Bh[64 * LDT], Bl[64 * LDT];
    const int tid = threadIdx.x;
    const int r = blockIdx.x, n0 = blockIdx.y * 64;
    const int wave = tid >> 6, lane = tid & 63;
    const int wr = wave >> 1, wc = wave & 1;
    const int lx = lane & 15, qd = lane >> 4;
    const int srow = tid >> 1, scol = (tid & 1) * 16;
    const int brow = tid >> 2, bcol = (tid & 3) * 8;

    const float* arow = Mb + (size_t)(r * 128 + srow) * 1024 + scol;
    const unsigned short* bhrow = CWh + ((size_t)r * 2048 + n0 + brow) * 1024 + bcol;
    const unsigned short* blrow = CWl + ((size_t)r * 2048 + n0 + brow) * 1024 + bcol;

    f32x4 acc[4][2];
#pragma unroll
    for (int i = 0; i < 4; i++)
#pragma unroll
        for (int j = 0; j < 2; j++) acc[i][j] = (f32x4){0.f, 0.f, 0.f, 0.f};

    for (int k0 = 0; k0 < 1024; k0 += 32) {
        float4 v0 = *(const float4*)(arow + k0);
        float4 v1 = *(const float4*)(arow + k0 + 4);
        float4 v2 = *(const float4*)(arow + k0 + 8);
        float4 v3 = *(const float4*)(arow + k0 + 12);
        float vv[16] = {v0.x, v0.y, v0.z, v0.w, v1.x, v1.y, v1.z, v1.w,
                        v2.x, v2.y, v2.z, v2.w, v3.x, v3.y, v3.z, v3.w};
        u16x8 p0, p1;
#pragma unroll
        for (int e = 0; e < 8; e++) p0[e] = f2bf(vv[e]);
#pragma unroll
        for (int e = 0; e < 8; e++) p1[e] = f2bf(vv[8 + e]);
        *(u16x8*)&Ah[srow * LDT + scol] = p0;
        *(u16x8*)&Ah[srow * LDT + scol + 8] = p1;
        *(u16x8*)&Bh[brow * LDT + bcol] = *(const u16x8*)(bhrow + k0);
        *(u16x8*)&Bl[brow * LDT + bcol] = *(const u16x8*)(blrow + k0);
        __syncthreads();

        bf16x8 fa[4], fbh[2], fbl[2];
#pragma unroll
        for (int i = 0; i < 4; i++)
            fa[i] = *(const bf16x8*)&Ah[(64 * wr + 16 * i + lx) * LDT + 8 * qd];
#pragma unroll
        for (int j = 0; j < 2; j++) {
            fbh[j] = *(const bf16x8*)&Bh[(32 * wc + 16 * j + lx) * LDT + 8 * qd];
            fbl[j] = *(const bf16x8*)&Bl[(32 * wc + 16 * j + lx) * LDT + 8 * qd];
        }
#pragma unroll
        for (int i = 0; i < 4; i++)
#pragma unroll
            for (int j = 0; j < 2; j++)
                acc[i][j] = __builtin_amdgcn_mfma_f32_16x16x32_bf16(fa[i], fbh[j], acc[i][j], 0, 0, 0);
#pragma unroll
        for (int i = 0; i < 4; i++)
#pragma unroll
            for (int j = 0; j < 2; j++)
                acc[i][j] = __builtin_amdgcn_mfma_f32_16x16x32_bf16(fa[i], fbl[j], acc[i][j], 0, 0, 0);
        __syncthreads();
    }

#pragma unroll
    for (int i = 0; i < 4; i++)
#pragma unroll
        for (int j = 0; j < 2; j++) {
            const int col = n0 + 32 * wc + 16 * j + lx;
#pragma unroll
            for (int p = 0; p < 4; p++) {
                const int row = 64 * wr + 16 * i + 4 * qd + p;
                V[((size_t)r * 128 + row) * 2048 + col] = acc[i][j][p];
            }
        }
}

// ---------------- k3 fallback: fp32 VALU (small-ws path) ----------------
__global__ __launch_bounds__(256) void k3_votes(const float* __restrict__ Mb,
                                                const float* __restrict__ CW,
                                                float* __restrict__ V) {
    __shared__ float As[16][132];
    __shared__ float Bs[16][132];
    const int tid = threadIdx.x;
    const int r = blockIdx.z;
    const int n0 = blockIdx.x * 128;
    const float* A = Mb + (size_t)r * 128 * 1024;
    const float* Bm = CW + (size_t)r * 1024 * 2048;
    float* C = V + (size_t)r * 128 * 2048;
    const int ty = tid >> 4, tx = tid & 15;
    const int k4 = (tid & 3) * 4, row = tid >> 2;
    const int n4 = (tid & 31) * 4, krow = tid >> 5;

    float acc[8][8];
#pragma unroll
    for (int i = 0; i < 8; i++)
#pragma unroll
        for (int j = 0; j < 8; j++) acc[i][j] = 0.f;

    for (int k0 = 0; k0 < 1024; k0 += 16) {
#pragma unroll
        for (int rr = 0; rr < 2; rr++) {
            const int m = row + rr * 64;
            float4 av = *(const float4*)(A + (size_t)m * 1024 + k0 + k4);
            As[k4 + 0][m] = av.x; As[k4 + 1][m] = av.y;
            As[k4 + 2][m] = av.z; As[k4 + 3][m] = av.w;
            const int k = krow + rr * 8;
            float4 bv = *(const float4*)(Bm + (size_t)(k0 + k) * 2048 + n0 + n4);
            *(float4*)(&Bs[k][n4]) = bv;
        }
        __syncthreads();
#pragma unroll
        for (int k = 0; k < 16; k++) {
            float a[8], b[8];
            *(float4*)(a)     = *(const float4*)(&As[k][ty * 8]);
            *(float4*)(a + 4) = *(const float4*)(&As[k][ty * 8 + 4]);
            *(float4*)(b)     = *(const float4*)(&Bs[k][tx * 8]);
            *(float4*)(b + 4) = *(const float4*)(&Bs[k][tx * 8 + 4]);
#pragma unroll
            for (int i = 0; i < 8; i++)
#pragma unroll
                for (int j = 0; j < 8; j++) acc[i][j] += a[i] * b[j];
        }
        __syncthreads();
    }
#pragma unroll
    for (int i = 0; i < 8; i++) {
        const int m = ty * 8 + i;
#pragma unroll
        for (int j = 0; j < 8; j += 4) {
            float4 v;
            v.x = acc[i][j + 0]; v.y = acc[i][j + 1];
            v.z = acc[i][j + 2]; v.w = acc[i][j + 3];
            *(float4*)(C + (size_t)m * 2048 + n0 + tx * 8 + j) = v;
        }
    }
}

// ---------------- k4: dynamic routing ----------------
__global__ __launch_bounds__(256) void k4_routing(const float* __restrict__ V,
                                                  float* __restrict__ out) {
    __shared__ float logits[8 * 128];
    __shared__ float route[8 * 128];
    __shared__ float preact[128 * 16];
    __shared__ float act[128 * 16];
    __shared__ float fred[128];
    const int b = blockIdx.x, tid = threadIdx.x;
    const float* vb = V + (size_t)b * 2048;

    for (int i = tid; i < 1024; i += 256) logits[i] = 0.f;
    __syncthreads();

    for (int it = 0; it < 3; it++) {
        {
            const int r = tid >> 5, g = tid & 31;
            float l[4];
#pragma unroll
            for (int q = 0; q < 4; q++) l[q] = logits[r * 128 + g + q * 32];
            float mx = fmaxf(fmaxf(l[0], l[1]), fmaxf(l[2], l[3]));
            for (int msk = 16; msk; msk >>= 1) mx = fmaxf(mx, __shfl_xor(mx, msk, 32));
            float e[4], s = 0.f;
#pragma unroll
            for (int q = 0; q < 4; q++) { e[q] = expf(l[q] - mx); s += e[q]; }
            for (int msk = 16; msk; msk >>= 1) s += __shfl_xor(s, msk, 32);
            float inv = 1.f / s;
#pragma unroll
            for (int q = 0; q < 4; q++) route[r * 128 + g + q * 32] = e[q] * inv;
        }
        __syncthreads();
        for (int i = tid; i < 2048; i += 256) {
            const int c = i >> 4;
            float a = 0.f;
#pragma unroll
            for (int r = 0; r < 8; r++)
                a += route[r * 128 + c] * vb[(size_t)r * 128 * 2048 + i];
            preact[i] = a;
        }
        __syncthreads();
        if (tid < 128) {
            float n2 = 0.f;
#pragma unroll
            for (int o = 0; o < 16; o++) { float p = preact[tid * 16 + o]; n2 += p * p; }
            fred[tid] = sqrtf(n2) / (1.f + n2);
        }
        __syncthreads();
        for (int i = tid; i < 2048; i += 256) act[i] = preact[i] * fred[i >> 4];
        __syncthreads();
        for (int i = tid; i < 1024; i += 256) {
            const int r = i >> 7, c = i & 127;
            float d = 0.f;
#pragma unroll
            for (int o = 0; o < 16; o++)
                d += vb[(size_t)r * 128 * 2048 + c * 16 + o] * act[c * 16 + o];
            logits[i] += d;
        }
        __syncthreads();
    }
    if (tid < 128) {
        float n2 = 0.f;
#pragma unroll
        for (int o = 0; o < 16; o++) { float a = act[tid * 16 + o]; n2 += a * a; }
        out[(size_t)b * 128 + tid] = sqrtf(n2);
    }
}

extern "C" void kernel_launch(void* const* d_in, const int* in_sizes, int n_in,
                              void* d_out, int out_size, void* d_ws, size_t ws_size,
                              hipStream_t stream) {
    const float* x   = (const float*)d_in[0];
    const float* WS1 = (const float*)d_in[1];
    const float* WS2 = (const float*)d_in[2];
    const float* cw  = (const float*)d_in[3];
    float* out = (float*)d_out;

    char* ws = (char*)d_ws;
    float* m_buf = (float*)ws;                                      // 4 MiB
    float* votes = (float*)(ws + ((size_t)4 << 20));                // 8 MiB

    const bool use_cw  = ws_size >= ((size_t)124 << 20);
    const bool use_big = ws_size >= ((size_t)188 << 20);

    if (use_big) {
        // --- big path: frag-direct. W1f@12, W2f@20, Xf@28, Hf@92 ---
        unsigned short* W1f = (unsigned short*)(ws + ((size_t)12 << 20)); // 8 MiB
        unsigned short* W2f = (unsigned short*)(ws + ((size_t)20 << 20)); // 8 MiB
        unsigned short* Xf  = (unsigned short*)(ws + ((size_t)28 << 20)); // 64 MiB
        unsigned short* Hf  = (unsigned short*)(ws + ((size_t)92 << 20)); // 64 MiB
        unsigned short* CWh = (unsigned short*)(ws + ((size_t)92 << 20)); // 32 MiB
        unsigned short* CWl = (unsigned short*)(ws + ((size_t)124 << 20)); // 32 MiB

        k0_w1frag<<<dim3(32, 8, 8), dim3(256), 0, stream>>>(WS1, W1f);
        k0_w2frag<<<dim3(16, 16, 8), dim3(256), 0, stream>>>(WS2, W2f);
        k0_xfrag<<<dim3(2048, 8), dim3(256), 0, stream>>>(x, Xf);

        for (int b0 = 0; b0 < 128; b0 += 32) {
            k1_frag<<<dim3(64, 4, 8), dim3(256), 0, stream>>>(
                Xf + (size_t)b0 * 256 * 1024, W1f, Hf);
            k2_frag<<<dim3(32, 16, 2), dim3(256), 0, stream>>>(
                Hf, W2f, x, m_buf, b0);
        }
        // Hf dead; overlay CWh/CWl and finish
        k0_tsplit<<<dim3(32, 16, 8), dim3(256), 0, stream>>>(cw, CWh, CWl);
        k3_votes_mfma<<<dim3(8, 32), dim3(256), 0, stream>>>(m_buf, CWh, CWl, votes);
    } else {
        // --- fallback path: round-4/5 flow with row-major W1h/W2h/Hh ---
        unsigned short* W1h = (unsigned short*)(ws + ((size_t)12 << 20));
        unsigned short* W2h = (unsigned short*)(ws + ((size_t)20 << 20));
        unsigned short* CWh = (unsigned short*)(ws + ((size_t)28 << 20));
        unsigned short* CWl = (unsigned short*)(ws + ((size_t)60 << 20));
        const size_t hh_off = use_cw ? ((size_t)92 << 20) : ((size_t)28 << 20);
        unsigned short* Hh = (unsigned short*)(ws + hh_off);

        const int nW4 = (8 * 512 * 1024) / 4;
        k0_hi<<<dim3((nW4 + 255) / 256), dim3(256), 0, stream>>>(WS1, W1h, nW4);
        k0_hi<<<dim3((nW4 + 255) / 256), dim3(256), 0, stream>>>(WS2, W2h, nW4);

        int CB = 128;
        {
            const size_t perb = (size_t)256 << 10;
            if (ws_size < hh_off + 128 * perb) {
                size_t avail = (ws_size > hh_off) ? (ws_size - hh_off) : perb;
                CB = (int)(avail / perb);
                if (CB < 1) CB = 1;
                if (CB > 128) CB = 128;
            }
        }

        if (use_cw)
            k0_tsplit<<<dim3(32, 16, 8), dim3(256), 0, stream>>>(cw, CWh, CWl);

        for (int b0 = 0; b0 < 128; b0 += CB) {
            const int bc = (128 - b0 < CB) ? (128 - b0) : CB;
            for (int r = 0; r < 8; r++) {
                k1_hbar_mfma<0><<<dim3(bc * 2, 4), dim3(256), 0, stream>>>(
                    (const void*)(x + (size_t)b0 * 256 * 1024),
                    W1h + (size_t)r * 512 * 1024, Hh);
                k2_mfma<<<dim3(bc, 16), dim3(256), 0, stream>>>(
                    Hh, W2h + (size_t)r * 1024 * 512, x, m_buf, b0, r);
            }
        }
        if (use_cw)
            k3_votes_mfma<<<dim3(8, 32), dim3(256), 0, stream>>>(m_buf, CWh, CWl, votes);
        else
            k3_votes<<<dim3(16, 1, 8), dim3(256), 0, stream>>>(m_buf, cw, votes);
    }
    k4_routing<<<dim3(128), dim3(256), 0, stream>>>(votes, out);
}